// Round 13
// baseline (34.450 us; speedup 1.0000x reference)
//
#include <hip/hip_runtime.h>

typedef float vf4 __attribute__((ext_vector_type(4)));

#define BATCH  8192
#define GROUPS 512
#define OUT_D  8
#define GCH    32                 // groups per block (chunk)
#define NCH    (GROUPS / GCH)     // 16 chunks
#define NSLOT  80                 // blocks per chunk; grid = 16*80 = 1280 = 5/CU exactly
#define SR     8                  // rows per stripe (2 per wave)
#define NSTR   (BATCH / SR)       // 1024 stripes
#define PQ     54                 // float4 per group in P
#define LQ     55                 // padded float4 per group in LDS

// Persistent-style: grid sized EXACTLY to residency (1280 = 5 blocks/CU at
// 27.5KB LDS) to eliminate block-generation quantization (~20% CU idle in
// R8-R12, where uniform-duration blocks ran in 2 generations, second 60%
// full). Each block stages its chunk's params once, then strides over 8-row
// stripes (12-13 per block, 1.6% imbalance). Next stripe's X is prefetched
// before the current stripe's compute. Gathers stay on the LDS pipe;
// stores stay 1KB-contiguous nontemporal.
__global__ __launch_bounds__(256) void hoact_kernel(
    const float* __restrict__ X,
    const float* __restrict__ P,
    float* __restrict__ out)
{
    __shared__ vf4 lp[GCH * LQ];       // 27.5 KB

    const int chunk = blockIdx.x % NCH;   // co-resident blocks share the chunk
    const int slot  = blockIdx.x / NCH;   // 0..79

    const int tid  = threadIdx.x;
    const int lane = tid & 63;
    const int w    = tid >> 6;
    const int gsub = lane >> 1;        // group within chunk 0..31
    const int h    = lane & 1;         // which 16B half of the param row

    // ---- stage params once: linear L2 read, padded LDS write ----
    const vf4* P4 = (const vf4*)P + (size_t)chunk * (GCH * PQ);
    #pragma unroll
    for (int k = 0; k < 7; ++k) {
        int m = tid + 256 * k;         // 0..1791, need < 1728
        if (m < GCH * PQ) {
            int gq = m / PQ;
            int iq = m - gq * PQ;
            lp[gq * LQ + iq] = P4[m];
        }
    }

    const int g = chunk * GCH + gsub;
    const float* xg = X + (size_t)g * 3;
    const size_t xrow  = GROUPS * 3;             // floats per X row
    const size_t row_u = GROUPS * OUT_D / 4;     // float4 units per out row
    vf4* outg = (vf4*)out + (size_t)chunk * (GCH * OUT_D / 4) + lane;
    const int base = gsub * LQ + h;

    // prologue: load first stripe's X (2 rows x 3 floats)
    float xc[6];
    {
        int r0 = slot * SR + w * 2;
        const float* xp0 = xg + (size_t)r0 * xrow;
        const float* xp1 = xg + (size_t)(r0 + 1) * xrow;
        xc[0] = xp0[0]; xc[1] = xp0[1]; xc[2] = xp0[2];
        xc[3] = xp1[0]; xc[4] = xp1[1]; xc[5] = xp1[2];
    }

    __syncthreads();

    #pragma unroll 1
    for (int t = slot; t < NSTR; t += NSLOT) {
        // prefetch next stripe's X before computing this one
        float xn[6];
        const int tn = t + NSLOT;
        if (tn < NSTR) {
            int r0 = tn * SR + w * 2;
            const float* xp0 = xg + (size_t)r0 * xrow;
            const float* xp1 = xg + (size_t)(r0 + 1) * xrow;
            xn[0] = xp0[0]; xn[1] = xp0[1]; xn[2] = xp0[2];
            xn[3] = xp1[0]; xn[4] = xp1[1]; xn[5] = xp1[2];
        }

        #pragma unroll
        for (int rr = 0; rr < 2; ++rr) {
            float x0 = xc[rr*3+0], x1 = xc[rr*3+1], x2 = xc[rr*3+2];

            float b0 = fabsf(x0), b1 = fabsf(x1), b2 = fabsf(x2);
            int t0 = (x0 >= 0.f) ? 1 : -1;
            int t1 = (x1 >= 0.f) ? 3 : -3;
            int t2 = (x2 >= 0.f) ? 9 : -9;
            // sort ascending by |x| (ties don't affect the result)
            if (b0 > b1) { float tb=b0; b0=b1; b1=tb; int tt=t0; t0=t1; t1=tt; }
            if (b1 > b2) { float tb=b1; b1=b2; b2=tb; int tt=t1; t1=t2; t2=tt; }
            if (b0 > b1) { float tb=b0; b0=b1; b1=tb; int tt=t0; t0=t1; t1=tt; }
            int i2 = t2 + 13;
            int i1 = t1 + t2 + 13;
            int i0 = t0 + t1 + t2 + 13;
            float c0 = b0;
            float c1 = b1 - b0;
            float c2 = b2 - b1;

            // LDS gathers: unit = gsub*55 + h + idx*2 (pair reads one 32B row)
            vf4 q0 = lp[base + i0 * 2];
            vf4 q1 = lp[base + i1 * 2];
            vf4 q2 = lp[base + i2 * 2];

            vf4 r = c0 * q0 + c1 * q1 + c2 * q2;

            // 64 lanes -> 64 consecutive float4 units: 1KB contiguous store
            int row = t * SR + w * 2 + rr;
            __builtin_nontemporal_store(r, outg + (size_t)row * row_u);
        }

        #pragma unroll
        for (int q = 0; q < 6; ++q) xc[q] = xn[q];
    }
}

extern "C" void kernel_launch(void* const* d_in, const int* in_sizes, int n_in,
                              void* d_out, int out_size, void* d_ws, size_t ws_size,
                              hipStream_t stream) {
    const float* X = (const float*)d_in[0];
    const float* P = (const float*)d_in[1];
    float* out = (float*)d_out;

    const int grid = NCH * NSLOT;   // 1280 blocks = 5 per CU exactly
    hoact_kernel<<<grid, 256, 0, stream>>>(X, P, out);
}

// Round 14
// 33.230 us; speedup vs baseline: 1.0367x; 1.0367x over previous
//
#include <hip/hip_runtime.h>

typedef float vf4 __attribute__((ext_vector_type(4)));

#define BATCH  8192
#define GROUPS 512
#define OUT_D  8
#define GCH    64                 // groups per block (quarter of an output row)
#define NCH    (GROUPS / GCH)     // 8 chunks
#define RT     64                 // batch rows per block (8 per wave)
#define RW     8                  // rows per wave
#define PQ     54                 // float4 per group in P (27*8 floats)
#define LQ     55                 // float4 per group in LDS (pad: 55%8=7 spreads bank-quads)

// R10 structure with the write RUN LENGTH doubled: chunk = 64 groups, so
// each wave emits 2 back-to-back 1KB store instructions = 2KB contiguous
// per row (testing whether DRAM write-run granularity is the ~24% residual
// over the mixed-traffic floor). 512-thread blocks, 56.3KB LDS -> 2
// blocks/CU (16 waves). Params LDS-gathered as before; X batched up front.
__global__ __launch_bounds__(512, 4) void hoact_kernel(
    const float* __restrict__ X,
    const float* __restrict__ P,
    float* __restrict__ out)
{
    __shared__ vf4 lp[GCH * LQ];       // 3520 vf4 = 56.3 KB

    const int chunk = blockIdx.x % NCH;   // co-resident blocks share the chunk
    const int rt    = blockIdx.x / NCH;

    const int tid  = threadIdx.x;
    const int lane = tid & 63;
    const int w    = tid >> 6;         // wave 0..7

    // ---- stage params for this chunk: linear L2 read, padded LDS write ----
    const vf4* P4 = (const vf4*)P + (size_t)chunk * (GCH * PQ);
    #pragma unroll
    for (int k = 0; k < 7; ++k) {
        int m = tid + 512 * k;         // 0..3583, need < 3456
        if (m < GCH * PQ) {
            int gq = m / PQ;
            int iq = m - gq * PQ;
            lp[gq * LQ + iq] = P4[m];
        }
    }

    // this lane's two output units per row: u = lane, lane+64
    const int gs0 = lane >> 1;         // group for sub 0 (0..31)
    const int gs1 = gs0 + 32;          // group for sub 1 (32..63)
    const int h   = lane & 1;

    // ---- batched X load: 48 dwords (8 rows x 2 groups x 3) ----
    const int row0 = rt * RT + w * RW;
    const float* xb = X + (size_t)row0 * (GROUPS * 3) + (size_t)chunk * (GCH * 3);
    float xv[RW][2][3];
    #pragma unroll
    for (int it = 0; it < RW; ++it) {
        const float* xr = xb + (size_t)it * (GROUPS * 3);
        const float* x0p = xr + gs0 * 3;
        const float* x1p = xr + gs1 * 3;
        xv[it][0][0] = x0p[0]; xv[it][0][1] = x0p[1]; xv[it][0][2] = x0p[2];
        xv[it][1][0] = x1p[0]; xv[it][1][1] = x1p[1]; xv[it][1][2] = x1p[2];
    }

    __syncthreads();

    const size_t row_u = GROUPS * OUT_D / 4;     // 1024 units per out row
    vf4* outb = (vf4*)out + (size_t)row0 * row_u
              + (size_t)chunk * (GCH * OUT_D / 4) + lane;
    const int base0 = gs0 * LQ + h;
    const int base1 = gs1 * LQ + h;

    #pragma unroll
    for (int it = 0; it < RW; ++it) {
        vf4 res[2];
        #pragma unroll
        for (int sub = 0; sub < 2; ++sub) {
            float x0 = xv[it][sub][0], x1 = xv[it][sub][1], x2 = xv[it][sub][2];

            float b0 = fabsf(x0), b1 = fabsf(x1), b2 = fabsf(x2);
            int t0 = (x0 >= 0.f) ? 1 : -1;
            int t1 = (x1 >= 0.f) ? 3 : -3;
            int t2 = (x2 >= 0.f) ? 9 : -9;
            // sort ascending by |x| (ties don't affect the result)
            if (b0 > b1) { float tb=b0; b0=b1; b1=tb; int tt=t0; t0=t1; t1=tt; }
            if (b1 > b2) { float tb=b1; b1=b2; b2=tb; int tt=t1; t1=t2; t2=tt; }
            if (b0 > b1) { float tb=b0; b0=b1; b1=tb; int tt=t0; t0=t1; t1=tt; }
            int i2 = t2 + 13;
            int i1 = t1 + t2 + 13;
            int i0 = t0 + t1 + t2 + 13;
            float c0 = b0;
            float c1 = b1 - b0;
            float c2 = b2 - b1;

            const int base = sub ? base1 : base0;
            vf4 q0 = lp[base + i0 * 2];
            vf4 q1 = lp[base + i1 * 2];
            vf4 q2 = lp[base + i2 * 2];

            res[sub] = c0 * q0 + c1 * q1 + c2 * q2;
        }

        // two back-to-back store instrs cover 128 units = 2KB contiguous
        vf4* dst = outb + (size_t)it * row_u;
        __builtin_nontemporal_store(res[0], dst);
        __builtin_nontemporal_store(res[1], dst + 64);
    }
}

extern "C" void kernel_launch(void* const* d_in, const int* in_sizes, int n_in,
                              void* d_out, int out_size, void* d_ws, size_t ws_size,
                              hipStream_t stream) {
    const float* X = (const float*)d_in[0];
    const float* P = (const float*)d_in[1];
    float* out = (float*)d_out;

    const int grid = (BATCH / RT) * NCH;   // 128 * 8 = 1024 blocks
    hoact_kernel<<<grid, 512, 0, stream>>>(X, P, out);
}